// Round 13
// baseline (230.842 us; speedup 1.0000x reference)
//
#include <hip/hip_runtime.h>

#define B_ 2
#define C_ 256
#define N_ 8192
#define NG_ 32

typedef unsigned int u32;
using f32x4  = __attribute__((ext_vector_type(4))) float;
using f32x16 = __attribute__((ext_vector_type(16))) float;
using s8v    = __attribute__((ext_vector_type(8))) short;   // 8 x bf16
using u32x2  = __attribute__((ext_vector_type(2))) u32;

__device__ __forceinline__ unsigned short f2bf(float f) {
  unsigned u = __builtin_bit_cast(unsigned, f);
  return (unsigned short)((u + 0x7fffu + ((u >> 16) & 1u)) >> 16);
}
__device__ __forceinline__ float bf2f(unsigned short h) {
  return __builtin_bit_cast(float, (u32)h << 16);
}
// pack two f32 -> two bf16 (RTNE) in one instr  [HW-verified R8-R12]
__device__ __forceinline__ u32 cvtpk(float lo, float hi) {
  u32 r;
  asm("v_cvt_pk_bf16_f32 %0, %1, %2" : "=v"(r) : "v"(lo), "v"(hi));
  return r;
}
// v_permlane32_swap_b32: newA=[a.row0,b.row0], newB=[a.row1,b.row1]  [HW-verified]
__device__ __forceinline__ void swap32u(u32& a, u32& b) {
  asm("v_permlane32_swap_b32 %0, %1" : "+v"(a), "+v"(b));
}
__device__ __forceinline__ float xhalf_max(float x) {
  float a = x, b = x;
  asm("v_permlane32_swap_b32 %0, %1" : "+v"(a), "+v"(b));
  return fmaxf(a, b);
}
__device__ __forceinline__ float xhalf_sum(float x) {
  float a = x, b = x;
  asm("v_permlane32_swap_b32 %0, %1" : "+v"(a), "+v"(b));
  return a + b;
}

// ------- prep: weight fp32->bf16 (folded) + two-level GN stats partials -----
__global__ __launch_bounds__(256) void prep_kernel(
    const float* __restrict__ x,
    const float* __restrict__ wq, const float* __restrict__ wk,
    const float* __restrict__ wv, const float* __restrict__ wp,
    unsigned short* __restrict__ wout, float* __restrict__ part) {
  int t = threadIdx.x, bi = blockIdx.x;
  int j = bi * 512 + t * 2;
  int m = j >> 16;
  const float* src = m == 0 ? wq : m == 1 ? wk : m == 2 ? wv : wp;
  int off = j & 65535;
  *(u32*)(wout + j) = cvtpk(src[off], src[off + 1]);
  int bg = bi >> 3, s = bi & 7;
  const float* xp = x + (size_t)bg * 8 * N_ + s * 1024;
  float sm = 0.f, sq = 0.f;
  for (int i = t; i < 2048; i += 256) {          // 8 rows x 256 f32x4
    int r = i >> 8, c4 = i & 255;
    f32x4 v = *(const f32x4*)(xp + (size_t)r * N_ + c4 * 4);
    sm += v.x + v.y + v.z + v.w;
    sq += v.x * v.x + v.y * v.y + v.z * v.z + v.w * v.w;
  }
  #pragma unroll
  for (int o = 32; o; o >>= 1) { sm += __shfl_down(sm, o); sq += __shfl_down(sq, o); }
  __shared__ float ls[4], lq[4];
  int w = t >> 6;
  if ((t & 63) == 0) { ls[w] = sm; lq[w] = sq; }
  __syncthreads();
  if (t == 0) {
    part[(bg * 8 + s) * 2]     = ls[0] + ls[1] + ls[2] + ls[3];
    part[(bg * 8 + s) * 2 + 1] = lq[0] + lq[1] + lq[2] + lq[3];
  }
}

// ------- fused GN-apply + QKV projection (h never materialized) -------------
// All three matrices use swapped mfma(W, h): D-row = out-channel j (lg*4+r),
// D-col = n (l15). Q/K stores become 8B u32x2 (4 consecutive j) via cvt_pk.
__global__ __launch_bounds__(512) void qkv_kernel(
    const float* __restrict__ x, const float* __restrict__ gw, const float* __restrict__ gb,
    const float* __restrict__ part, const unsigned short* __restrict__ wqkv,
    const float* __restrict__ bq, const float* __restrict__ bk, const float* __restrict__ bv,
    unsigned short* __restrict__ Qo, unsigned short* __restrict__ Ko,
    unsigned short* __restrict__ Vo) {
  __shared__ u32 hx[256][38];                    // [c][n-pair] bf16x2
  __shared__ float gmean[32], grstd[32];
  __shared__ float scl[256], sft[256];
  const size_t HS = (size_t)N_ * C_;
  int b = blockIdx.y, n0 = blockIdx.x * 64;
  int t = threadIdx.x;

  if (t < 32) {
    float sm = 0.f, sq = 0.f;
    #pragma unroll
    for (int s = 0; s < 8; ++s) {
      sm += part[((b * 32 + t) * 8 + s) * 2];
      sq += part[((b * 32 + t) * 8 + s) * 2 + 1];
    }
    float mean = sm * (1.f / 65536.f);
    float var = sq * (1.f / 65536.f) - mean * mean;
    gmean[t] = mean;
    grstd[t] = rsqrtf(var + 1e-5f);
  }
  __syncthreads();
  if (t < 256) {
    int g = t >> 3;
    float s0 = grstd[g] * gw[t];
    scl[t] = s0;
    sft[t] = gb[t] - gmean[g] * s0;
  }
  __syncthreads();

  {
    int col2 = (t & 31) * 2;
    int c0 = t >> 5;
    const float* xb = x + (size_t)b * C_ * N_ + n0 + col2;
    #pragma unroll
    for (int r = 0; r < 16; ++r) {
      int c = r * 16 + c0;
      const float* xp = xb + (size_t)c * N_;
      float v0 = __builtin_fmaf(xp[0], scl[c], sft[c]);
      float v1 = __builtin_fmaf(xp[1], scl[c], sft[c]);
      hx[c][t & 31] = cvtpk(v0, v1);
    }
  }
  __syncthreads();

  int lane = t & 63, w = t >> 6;
  int l15 = lane & 15, lg = lane >> 4;
  int rbase = (w >> 1) * 16 + l15;
  s8v a[8];
  #pragma unroll
  for (int kt = 0; kt < 8; ++kt) {
    #pragma unroll
    for (int e = 0; e < 8; ++e) {
      u32 wd = hx[kt * 32 + lg * 8 + e][rbase >> 1];
      a[kt][e] = (short)(unsigned short)(wd >> ((rbase & 1) * 16));
    }
  }

  int gn = n0 + (w >> 1) * 16;
  int jb0 = (w & 1) * 2;
  #pragma unroll
  for (int m = 0; m < 3; ++m) {
    const unsigned short* W = wqkv + m * 65536;
    const float* bias = m == 0 ? bq : m == 1 ? bk : bv;
    #pragma unroll
    for (int jx = 0; jx < 2; ++jx) {
      int j0 = (jb0 + jx) * 64;
      f32x4 acc[4];
      #pragma unroll
      for (int jt = 0; jt < 4; ++jt) acc[jt] = f32x4{0.f, 0.f, 0.f, 0.f};
      #pragma unroll
      for (int kt = 0; kt < 8; ++kt) {
        #pragma unroll
        for (int jt = 0; jt < 4; ++jt) {
          s8v bb = *(const s8v*)(W + (size_t)(j0 + jt * 16 + l15) * 256 + kt * 32 + lg * 8);
          acc[jt] = __builtin_amdgcn_mfma_f32_16x16x32_bf16(bb, a[kt], acc[jt], 0, 0, 0);
        }
      }
      if (m < 2) {
        // D-row = j (lg*4+r), D-col = n (l15): pack 4 consecutive j, 8B store
        unsigned short* o = (m == 0 ? Qo : Ko) + (size_t)b * HS + (size_t)(gn + l15) * 256;
        #pragma unroll
        for (int jt = 0; jt < 4; ++jt) {
          int j = j0 + jt * 16 + lg * 4;
          f32x4 bv4 = *(const f32x4*)(bias + j);
          u32x2 pk;
          pk.x = cvtpk(acc[jt][0] + bv4.x, acc[jt][1] + bv4.y);
          pk.y = cvtpk(acc[jt][2] + bv4.z, acc[jt][3] + bv4.w);
          *(u32x2*)(o + j) = pk;
        }
      } else {
        unsigned short* o = Vo + (size_t)b * HS;
        int nn = gn + l15;
        #pragma unroll
        for (int jt = 0; jt < 4; ++jt) {
          f32x4 bv4 = *(const f32x4*)(bias + j0 + jt * 16 + lg * 4);
          #pragma unroll
          for (int r = 0; r < 4; ++r) {
            int oc = j0 + jt * 16 + lg * 4 + r;
            o[(size_t)oc * N_ + nn] = f2bf(acc[jt][r] + bv4[r]);
          }
        }
      }
    }
  }
}

// ---------------- flash attention pass 1 (UNCHANGED, parked at cap) ---------
__global__ __launch_bounds__(256, 2) void attn_kernel(
    const unsigned short* __restrict__ Q, const unsigned short* __restrict__ K,
    const unsigned short* __restrict__ V, unsigned short* __restrict__ Op,
    float* __restrict__ lse) {
  extern __shared__ unsigned short smem[];
  int f = blockIdx.x;
  int grp = f & 7, qb = f >> 3;
  int sl = grp & 3, b = grp >> 2;
  int q0 = qb * 128;
  int kvbase = sl * 2048;
  int t = threadIdx.x, lane = t & 63, w = t >> 6;
  int l31 = lane & 31, hi = lane >> 5;

  const unsigned short* Qg = Q + ((size_t)b * N_ + q0 + w * 32 + l31) * 256;
  const unsigned short* Kg = K + ((size_t)b * N_ + kvbase) * 256;
  const unsigned short* Vg = V + (size_t)b * 256 * N_ + kvbase;
  const float sc = 0.0625f * 1.44269504088896f;          // C^-0.5 * log2(e)

  s8v qf[16];
  #pragma unroll
  for (int tt = 0; tt < 16; ++tt)
    qf[tt] = *(const s8v*)(Qg + tt * 16 + hi * 8);

  f32x16 o_acc[8];
  #pragma unroll
  for (int dc = 0; dc < 8; ++dc)
    #pragma unroll
    for (int r = 0; r < 16; ++r) o_acc[dc][r] = 0.f;
  float m_r = -1e30f, l_r = 0.f;

  auto stage = [&](int it, int bufsel) {
    char* Kd = (char*)smem + bufsel * 16384;
    char* Vd = (char*)smem + 32768 + bufsel * 16384;
    const unsigned short* Ks = Kg + (size_t)it * 32 * 256;
    const unsigned short* Vs = Vg + it * 32;
    #pragma unroll
    for (int i = 0; i < 4; ++i) {
      int u = i * 256 + t;
      int mm = u >> 5, j = u & 31;
      const unsigned short* src = Ks + mm * 256 + ((j ^ mm) * 8);
      char* dst = Kd + (i * 256 + w * 64) * 16;
      __builtin_amdgcn_global_load_lds(
          (const __attribute__((address_space(1))) u32*)src,
          (__attribute__((address_space(3))) u32*)dst, 16, 0, 0);
    }
    #pragma unroll
    for (int i = 0; i < 4; ++i) {
      const unsigned short* src = Vs + (size_t)t * N_ + i * 8;
      char* dst = Vd + (i * 256 + w * 64) * 16;
      __builtin_amdgcn_global_load_lds(
          (const __attribute__((address_space(1))) u32*)src,
          (__attribute__((address_space(3))) u32*)dst, 16, 0, 0);
    }
  };

  stage(0, 0);
  __syncthreads();

  for (int it = 0; it < 64; ++it) {
    int cur = it & 1;
    if (it + 1 < 64) stage(it + 1, cur ^ 1);
    const char* Kd = (const char*)smem + cur * 16384;
    const char* Vd = (const char*)smem + 32768 + cur * 16384;

    f32x16 sa;
    #pragma unroll
    for (int r = 0; r < 16; ++r) sa[r] = 0.f;
    __builtin_amdgcn_s_setprio(1);
    #pragma unroll
    for (int tt = 0; tt < 16; ++tt) {
      int slot = 2 * tt + hi;
      s8v ka = *(const s8v*)(Kd + l31 * 512 + ((slot ^ l31) * 16));
      sa = __builtin_amdgcn_mfma_f32_32x32x16_bf16(ka, qf[tt], sa, 0, 0, 0);
    }
    __builtin_amdgcn_s_setprio(0);

    float rmax = sa[0];
    #pragma unroll
    for (int r = 1; r < 16; ++r) rmax = fmaxf(rmax, sa[r]);
    rmax = xhalf_max(rmax);
    rmax *= sc;
    if (!__all(rmax <= m_r + 8.f)) {
      float mn = fmaxf(m_r, rmax);
      float corr = exp2f(m_r - mn);
      m_r = mn;
      l_r *= corr;
      #pragma unroll
      for (int dc = 0; dc < 8; ++dc)
        #pragma unroll
        for (int r = 0; r < 16; ++r) o_acc[dc][r] *= corr;
    }
    float rs = 0.f;
    u32 wv[8];
    #pragma unroll
    for (int j = 0; j < 8; ++j) {
      float p0 = exp2f(__builtin_fmaf(sa[2 * j],     sc, -m_r));
      float p1 = exp2f(__builtin_fmaf(sa[2 * j + 1], sc, -m_r));
      rs += p0 + p1;
      wv[j] = cvtpk(p0, p1);
    }
    l_r += xhalf_sum(rs);

    swap32u(wv[0], wv[2]);
    swap32u(wv[1], wv[3]);
    swap32u(wv[4], wv[6]);
    swap32u(wv[5], wv[7]);
    union { u32 u[4]; s8v v; } pf0, pf1;
    pf0.u[0] = wv[0]; pf0.u[1] = wv[1]; pf0.u[2] = wv[2]; pf0.u[3] = wv[3];
    pf1.u[0] = wv[4]; pf1.u[1] = wv[5]; pf1.u[2] = wv[6]; pf1.u[3] = wv[7];

    __builtin_amdgcn_s_setprio(1);
    #pragma unroll
    for (int dc = 0; dc < 8; ++dc) {
      s8v va0 = *(const s8v*)(Vd + ((hi) * 256 + dc * 32 + l31) * 16);
      o_acc[dc] = __builtin_amdgcn_mfma_f32_32x32x16_bf16(va0, pf0.v, o_acc[dc], 0, 0, 0);
      s8v va1 = *(const s8v*)(Vd + ((2 + hi) * 256 + dc * 32 + l31) * 16);
      o_acc[dc] = __builtin_amdgcn_mfma_f32_32x32x16_bf16(va1, pf1.v, o_acc[dc], 0, 0, 0);
    }
    __builtin_amdgcn_s_setprio(0);
    __syncthreads();
  }

  float inv = 1.f / l_r;
  size_t rid = (size_t)b * N_ + q0 + w * 32 + l31;
  if (!hi) lse[(size_t)sl * (B_ * N_) + rid] = m_r + log2f(l_r);
  unsigned short* Od = Op + ((size_t)sl * (B_ * N_) + rid) * 256;
  #pragma unroll
  for (int dc = 0; dc < 8; ++dc) {
    #pragma unroll
    for (int rg = 0; rg < 4; ++rg) {
      int d0 = dc * 32 + 8 * rg + 4 * hi;
      u32 w0 = cvtpk(o_acc[dc][rg * 4 + 0] * inv, o_acc[dc][rg * 4 + 1] * inv);
      u32 w1 = cvtpk(o_acc[dc][rg * 4 + 2] * inv, o_acc[dc][rg * 4 + 3] * inv);
      u32x2 pk{w0, w1};
      *(u32x2*)(Od + d0) = pk;
    }
  }
}

// ------- fused merge + output projection: out = wp . mergedO + bp + x -------
// 64 n-rows/block, 512 thr (8 waves = 2/SIMD), grid 256 (1/CU). Phase 1:
// merge 4 KV-slice partials -> LDS [64 n][32 slot][8 c], slot^=(row&31) XOR.
// Phase 2: wave w owns 32 channels; aa (wp) reused across 4 n-subtiles, so
// wp L2 traffic halves vs 32-row blocks. Epilogue + bias + fp32 residual.
__global__ __launch_bounds__(512) void out_kernel(
    const unsigned short* __restrict__ Op, const float* __restrict__ lse,
    const unsigned short* __restrict__ W, const float* __restrict__ bias,
    const float* __restrict__ x, float* __restrict__ out) {
  __shared__ unsigned short hx[64][32][8];       // 32 KB
  int b = blockIdx.y, n0 = blockIdx.x * 64;
  int t = threadIdx.x;

  // ---- merge phase: thread -> row t>>3 (0..63), ch8 t&7 ----
  int row = t >> 3;
  int ch8 = t & 7;
  size_t rid = (size_t)b * N_ + n0 + row;
  float L[4], lm = -1e30f;
  #pragma unroll
  for (int s = 0; s < 4; ++s) {
    L[s] = lse[(size_t)s * (B_ * N_) + rid];
    lm = fmaxf(lm, L[s]);
  }
  float wg[4], wsum = 0.f;
  #pragma unroll
  for (int s = 0; s < 4; ++s) { wg[s] = exp2f(L[s] - lm); wsum += wg[s]; }
  float inv = 1.f / wsum;
  #pragma unroll
  for (int s = 0; s < 4; ++s) wg[s] *= inv;
  #pragma unroll
  for (int cb = 0; cb < 4; ++cb) {
    int chunk = cb * 8 + ch8;                     // 0..31
    float acc[8];
    #pragma unroll
    for (int e = 0; e < 8; ++e) acc[e] = 0.f;
    #pragma unroll
    for (int s = 0; s < 4; ++s) {
      s8v v = *(const s8v*)(Op + ((size_t)s * (B_ * N_) + rid) * 256 + chunk * 8);
      #pragma unroll
      for (int e = 0; e < 8; ++e)
        acc[e] = __builtin_fmaf(wg[s], bf2f((unsigned short)v[e]), acc[e]);
    }
    union { u32 u[4]; s8v v; } pk;
    pk.u[0] = cvtpk(acc[0], acc[1]);
    pk.u[1] = cvtpk(acc[2], acc[3]);
    pk.u[2] = cvtpk(acc[4], acc[5]);
    pk.u[3] = cvtpk(acc[6], acc[7]);
    *(s8v*)&hx[row][chunk ^ (row & 31)][0] = pk.v;   // XOR swizzle
  }
  __syncthreads();

  // ---- GEMM phase: wave w owns channels w*32..w*32+31 ----
  int lane = t & 63, w = t >> 6;
  int l15 = lane & 15, lg = lane >> 4;
  f32x4 acc[2][4];
  #pragma unroll
  for (int ct = 0; ct < 2; ++ct)
    #pragma unroll
    for (int jt = 0; jt < 4; ++jt) acc[ct][jt] = f32x4{0.f, 0.f, 0.f, 0.f};
  #pragma unroll
  for (int kt = 0; kt < 8; ++kt) {
    s8v bb[4];
    #pragma unroll
    for (int jt = 0; jt < 4; ++jt) {
      int n = jt * 16 + l15;
      bb[jt] = *(const s8v*)&hx[n][(kt * 4 + lg) ^ (n & 31)][0];
    }
    #pragma unroll
    for (int ct = 0; ct < 2; ++ct) {
      s8v aa = *(const s8v*)(W + (size_t)(w * 32 + ct * 16 + l15) * 256 + kt * 32 + lg * 8);
      #pragma unroll
      for (int jt = 0; jt < 4; ++jt)
        acc[ct][jt] = __builtin_amdgcn_mfma_f32_16x16x32_bf16(aa, bb[jt], acc[ct][jt], 0, 0, 0);
    }
  }
  // epilogue: out[b][c][n] = acc + bias[c] + x[b][c][n]
  #pragma unroll
  for (int ct = 0; ct < 2; ++ct) {
    #pragma unroll
    for (int r = 0; r < 4; ++r) {
      int c = w * 32 + ct * 16 + lg * 4 + r;
      float bc = bias[c];
      size_t base = ((size_t)b * C_ + c) * N_ + n0;
      #pragma unroll
      for (int jt = 0; jt < 4; ++jt) {
        int n = jt * 16 + l15;
        out[base + n] = acc[ct][jt][r] + bc + x[base + n];
      }
    }
  }
}

// ---------------------------------------------------------------------------
extern "C" void kernel_launch(void* const* d_in, const int* in_sizes, int n_in,
                              void* d_out, int out_size, void* d_ws, size_t ws_size,
                              hipStream_t stream) {
  (void)in_sizes; (void)n_in; (void)out_size; (void)ws_size;
  const float* x  = (const float*)d_in[0];
  const float* gw = (const float*)d_in[1];
  const float* gb = (const float*)d_in[2];
  const float* wq = (const float*)d_in[3];
  const float* bq = (const float*)d_in[4];
  const float* wk = (const float*)d_in[5];
  const float* bk = (const float*)d_in[6];
  const float* wv = (const float*)d_in[7];
  const float* bv = (const float*)d_in[8];
  const float* wp = (const float*)d_in[9];
  const float* bp = (const float*)d_in[10];

  const size_t HS = (size_t)N_ * C_;              // per-batch elems
  char* ws = (char*)d_ws;
  unsigned short* wqb = (unsigned short*)ws;             // 512 KB [wq|wk|wv|wp]
  float* part = (float*)(ws + 524288);                   // 4 KB [64][8][2]
  unsigned short* Qb   = (unsigned short*)(ws + 528384); // 8 MB  [B][N][C]
  unsigned short* Kb   = Qb + B_ * HS;                   // 8 MB  [B][N][C]
  unsigned short* Vb   = Kb + B_ * HS;                   // 8 MB  [B][C][N]
  unsigned short* Opart = Vb + B_ * HS;                  // 32 MB [4][B*N][C]
  float* lsep = (float*)(Opart + 4 * B_ * HS);           // 256 KB [4][B*N]

  // prep: weight cvt + GN stats partials (512 blocks, full-chip BW)
  prep_kernel<<<512, 256, 0, stream>>>(x, wq, wk, wv, wp, wqb, part);

  // fused GN-apply + QKV projection
  qkv_kernel<<<dim3(N_ / 64, B_), 512, 0, stream>>>(
      x, gw, gb, part, wqb, bq, bk, bv, Qb, Kb, Vb);

  // flash attention pass 1: swapped-QK^T 32x32 + T12, 4 KV slices
  const int attn_lds = 65536;
  hipFuncSetAttribute(reinterpret_cast<const void*>(attn_kernel),
                      hipFuncAttributeMaxDynamicSharedMemorySize, attn_lds);
  attn_kernel<<<dim3(512), 256, attn_lds, stream>>>(Qb, Kb, Vb, Opart, lsep);

  // fused merge + output projection + residual (64 n-rows/block)
  unsigned short* wpb = wqb + 3 * 65536;
  out_kernel<<<dim3(N_ / 64, B_), 512, 0, stream>>>(
      Opart, lsep, wpb, bp, x, (float*)d_out);
}